// Round 16
// baseline (233.177 us; speedup 1.0000x reference)
//
#include <hip/hip_runtime.h>

#define NF 40
#define NF4 10
#define H  64
#define NC 3
#define BK 256        // nodes per bucket (dst>>8)
#define CAP 10240     // staging capacity per bucket (mean 8192, +22 sigma)
#define MAXNBK 512
#define SMASK 0xFFFFFu
#define EPB 6400      // edges per k_bin2 block

// --- zero ints ---
__global__ void k_zero(int* __restrict__ p, int n) {
    int i = blockIdx.x * blockDim.x + threadIdx.x;
    if (i < n) p[i] = 0;
}

// --- partition: block-local bucket sort in LDS, then coalesced window writes ---
__global__ __launch_bounds__(512) void k_bin2(const int* __restrict__ src,
                                              const int* __restrict__ dst,
                                              int* __restrict__ gcur,
                                              unsigned* __restrict__ staging,
                                              int ne, int nbk) {
    __shared__ unsigned sorted[EPB];               // 25.6 KB
    __shared__ unsigned short sbk[EPB];            // 12.8 KB
    __shared__ int cnt[MAXNBK];
    __shared__ int tsum[MAXNBK];
    __shared__ int lstart[MAXNBK];
    __shared__ int gbase[MAXNBK];
    __shared__ int cur[MAXNBK];
    int t = threadIdx.x;
    int e0 = blockIdx.x * EPB;
    int m = min(EPB, ne - e0);
    if (m <= 0) return;

    for (int b = t; b < MAXNBK; b += 512) cnt[b] = 0;
    __syncthreads();
    for (int j = t; j < m; j += 512)               // pass 1: bucket histogram
        atomicAdd(&cnt[dst[e0 + j] >> 8], 1);
    __syncthreads();
    int val = (t < nbk) ? cnt[t] : 0;              // block-wide exclusive scan (512)
    tsum[t] = val;
    __syncthreads();
    for (int off = 1; off < 512; off <<= 1) {
        int a = (t >= off) ? tsum[t - off] : 0;
        __syncthreads();
        tsum[t] += a;
        __syncthreads();
    }
    lstart[t] = tsum[t] - val;
    cur[t] = tsum[t] - val;
    if (t < nbk) gbase[t] = val ? atomicAdd(&gcur[t], val) : 0;   // reserve windows
    __syncthreads();
    for (int j = t; j < m; j += 512) {             // pass 2: LDS scatter (bucket order)
        int d = dst[e0 + j], s = src[e0 + j];
        int b = d >> 8;
        int p = atomicAdd(&cur[b], 1);
        sorted[p] = ((unsigned)(d & 255) << 20) | (unsigned)s;
        sbk[p] = (unsigned short)b;
    }
    __syncthreads();
    for (int j = t; j < m; j += 512) {             // pass 3: near-coalesced writes
        int b = sbk[j];
        staging[(size_t)b * CAP + gbase[b] + (j - lstart[b])] = sorted[j];
    }
}

// --- per-bucket sort by dlocal (in place via LDS bounce); emits rs/rl/dinv ---
__global__ __launch_bounds__(512) void k_sort(unsigned* __restrict__ staging,
                                              const int* __restrict__ gcur,
                                              int* __restrict__ rs, int* __restrict__ rl,
                                              float* __restrict__ dinv, int n) {
    __shared__ unsigned buf[CAP];      // 40 KB bounce buffer
    __shared__ int cnt[BK];
    __shared__ int scn[BK];
    __shared__ int cur[BK];
    int b = blockIdx.x, t = threadIdx.x;
    int ebase = b * CAP;
    int rlen = gcur[b];
    for (int j = t; j < rlen; j += 512) buf[j] = staging[ebase + j];
    if (t < BK) cnt[t] = 0;
    __syncthreads();
    for (int j = t; j < rlen; j += 512)
        atomicAdd(&cnt[buf[j] >> 20], 1);
    __syncthreads();
    if (t < BK) scn[t] = cnt[t];
    __syncthreads();
    for (int off = 1; off < BK; off <<= 1) {       // inclusive Hillis-Steele
        int a = (t < BK && t >= off) ? scn[t - off] : 0;
        __syncthreads();
        if (t < BK) scn[t] += a;
        __syncthreads();
    }
    if (t < BK) {
        int deg = cnt[t];
        int excl = scn[t] - deg;
        cur[t] = excl;
        int node = b * BK + t;
        if (node < n) {
            rs[node] = ebase + excl;
            rl[node] = deg;
            dinv[node] = rsqrtf((float)(deg + 1));
        }
    }
    __syncthreads();
    for (int j = t; j < rlen; j += 512) {          // scatter back sorted by dlocal
        unsigned e = buf[j];
        int p = atomicAdd(&cur[e >> 20], 1);
        staging[ebase + p] = e;
    }
}

// --- FUSED pull1 + MLP: each wave gathers 32 nodes' ax into its private LDS tile
//     (transposed), then runs the register-tiled MLP there. MLP VALU work of one
//     wave hides under other waves' gather stalls. NO block barriers anywhere.
__global__ __launch_bounds__(256, 4) void k_fused(
        const unsigned* __restrict__ st, const int* __restrict__ rs,
        const int* __restrict__ rl, const float* __restrict__ dinv,
        const float4* __restrict__ x4,
        const float* __restrict__ W1, const float* __restrict__ b1,
        const float* __restrict__ Wf, const float* __restrict__ bf,
        const float* __restrict__ W2, float4* __restrict__ s2sp4, int n) {
    __shared__ float hT[4][H * 32];                // 8 KB/wave; rows 0..39 double as axT
    int t = threadIdx.x, w = t >> 6, lane = t & 63;
    int g = lane / 10, f = lane - g * 10;          // 6 slots x 10 float4-lanes
    int nb0 = (blockIdx.x * 4 + w) * 32;
    if (nb0 >= n) return;                          // per-wave uniform; no barriers used
    int cnt = min(32, n - nb0);
    float* axT = &hT[w][0];
    float4 z = make_float4(0.f, 0.f, 0.f, 0.f);

    // ---- phase 1: gather 32 nodes, one at a time (whole wave per node) ----
    for (int no = 0; no < cnt; ++no) {
        int d = nb0 + no;
        int beg = rs[d], len = rl[d];
        float dd = dinv[d];
        float4 acc = z;
        if (g < 6) {
            int j = beg + g, end = beg + len;
            if (j < end) {
                // 2-stage software pipeline: prefetch next pair's st before FMA
                unsigned e0 = st[j];
                bool p1 = (j + 6 < end);
                unsigned e1 = p1 ? st[j + 6] : 0u;
                int s0 = (int)(e0 & SMASK), s1 = (int)(e1 & SMASK);
                float w0 = dinv[s0];
                float w1 = p1 ? dinv[s1] : 0.f;
                float4 v0 = x4[(size_t)s0 * NF4 + f];
                float4 v1 = p1 ? x4[(size_t)s1 * NF4 + f] : z;
                j += 12;
                while (j < end) {
                    unsigned f0 = st[j];
                    bool q1 = (j + 6 < end);
                    unsigned f1 = q1 ? st[j + 6] : 0u;
                    acc.x += v0.x * w0 + v1.x * w1;
                    acc.y += v0.y * w0 + v1.y * w1;
                    acc.z += v0.z * w0 + v1.z * w1;
                    acc.w += v0.w * w0 + v1.w * w1;
                    int t0 = (int)(f0 & SMASK), t1 = (int)(f1 & SMASK);
                    w0 = dinv[t0];
                    w1 = q1 ? dinv[t1] : 0.f;
                    v0 = x4[(size_t)t0 * NF4 + f];
                    v1 = q1 ? x4[(size_t)t1 * NF4 + f] : z;
                    j += 12;
                }
                acc.x += v0.x * w0 + v1.x * w1;
                acc.y += v0.y * w0 + v1.y * w1;
                acc.z += v0.z * w0 + v1.z * w1;
                acc.w += v0.w * w0 + v1.w * w1;
            }
        }
        // slot-reduce via shfl tree: (g)+(g+3), then +10, +20  (all lanes execute)
        float4 t1v;
        t1v.x = acc.x + __shfl(acc.x, lane + 30);
        t1v.y = acc.y + __shfl(acc.y, lane + 30);
        t1v.z = acc.z + __shfl(acc.z, lane + 30);
        t1v.w = acc.w + __shfl(acc.w, lane + 30);
        float4 tot;
        tot.x = t1v.x + __shfl(t1v.x, lane + 10) + __shfl(t1v.x, lane + 20);
        tot.y = t1v.y + __shfl(t1v.y, lane + 10) + __shfl(t1v.y, lane + 20);
        tot.z = t1v.z + __shfl(t1v.z, lane + 10) + __shfl(t1v.z, lane + 20);
        tot.w = t1v.w + __shfl(t1v.w, lane + 10) + __shfl(t1v.w, lane + 20);
        if (lane < NF4) {
            float4 self = x4[(size_t)d * NF4 + lane];
            axT[(4 * lane + 0) * 32 + no] = dd * (tot.x + self.x * dd);
            axT[(4 * lane + 1) * 32 + no] = dd * (tot.y + self.y * dd);
            axT[(4 * lane + 2) * 32 + no] = dd * (tot.z + self.z * dd);
            axT[(4 * lane + 3) * 32 + no] = dd * (tot.w + self.w * dd);
        }
    }
    if (cnt < 32 && lane < NF)                     // zero tail columns for the GEMM
        for (int no2 = cnt; no2 < 32; ++no2)
            axT[lane * 32 + no2] = 0.f;
    // same-wave in-order DS: GEMM reads below see the staging writes

    // ---- phase 2: register-tiled wave-GEMM MLP (weights from global, L1/L2-hot) ---
    int r = lane & 7, c = lane >> 3;
    float bb[8], bfv[8], w2s[8][3];
    #pragma unroll
    for (int j = 0; j < 8; ++j) {
        bb[j]  = b1[8 * c + j];
        bfv[j] = bf[8 * c + j];
        w2s[j][0] = W2[(8 * c + j) * NC + 0];
        w2s[j][1] = W2[(8 * c + j) * NC + 1];
        w2s[j][2] = W2[(8 * c + j) * NC + 2];
    }

    float acc1[4][8];
    #pragma unroll
    for (int i = 0; i < 4; ++i)
        #pragma unroll
        for (int j = 0; j < 8; ++j) acc1[i][j] = bb[j];
    for (int k = 0; k < NF; ++k) {
        float4 a   = *(const float4*)&axT[k * 32 + 4 * r];
        float4 blo = *(const float4*)&W1[k * H + 8 * c];
        float4 bhi = *(const float4*)&W1[k * H + 8 * c + 4];
        float av[4] = {a.x, a.y, a.z, a.w};
        float bv[8] = {blo.x, blo.y, blo.z, blo.w, bhi.x, bhi.y, bhi.z, bhi.w};
        #pragma unroll
        for (int i = 0; i < 4; ++i)
            #pragma unroll
            for (int j = 0; j < 8; ++j) acc1[i][j] = fmaf(av[i], bv[j], acc1[i][j]);
    }
    #pragma unroll
    for (int j = 0; j < 8; ++j) {                  // write h transposed (after all reads)
        float4 hv = make_float4(fmaxf(acc1[0][j], 0.f), fmaxf(acc1[1][j], 0.f),
                                fmaxf(acc1[2][j], 0.f), fmaxf(acc1[3][j], 0.f));
        *(float4*)&hT[w][(8 * c + j) * 32 + 4 * r] = hv;
    }

    float acc2[4][8];
    #pragma unroll
    for (int i = 0; i < 4; ++i)
        #pragma unroll
        for (int j = 0; j < 8; ++j) acc2[i][j] = bfv[j];
    for (int k = 0; k < H; ++k) {
        float4 a   = *(const float4*)&hT[w][k * 32 + 4 * r];
        float4 blo = *(const float4*)&Wf[k * H + 8 * c];
        float4 bhi = *(const float4*)&Wf[k * H + 8 * c + 4];
        float av[4] = {a.x, a.y, a.z, a.w};
        float bv[8] = {blo.x, blo.y, blo.z, blo.w, bhi.x, bhi.y, bhi.z, bhi.w};
        #pragma unroll
        for (int i = 0; i < 4; ++i)
            #pragma unroll
            for (int j = 0; j < 8; ++j) acc2[i][j] = fmaf(av[i], bv[j], acc2[i][j]);
    }

    float p0[4], p1[4], p2[4];
    #pragma unroll
    for (int i = 0; i < 4; ++i) { p0[i] = 0.f; p1[i] = 0.f; p2[i] = 0.f; }
    #pragma unroll
    for (int i = 0; i < 4; ++i)
        #pragma unroll
        for (int j = 0; j < 8; ++j) {
            float s = (acc2[i][j] >= 0.5f) ? 1.f : 0.f;
            p0[i] = fmaf(s, w2s[j][0], p0[i]);
            p1[i] = fmaf(s, w2s[j][1], p1[i]);
            p2[i] = fmaf(s, w2s[j][2], p2[i]);
        }
    #pragma unroll
    for (int off = 8; off < 64; off <<= 1) {
        #pragma unroll
        for (int i = 0; i < 4; ++i) {
            p0[i] += __shfl_xor(p0[i], off);
            p1[i] += __shfl_xor(p1[i], off);
            p2[i] += __shfl_xor(p2[i], off);
        }
    }
    if (c == 0) {
        #pragma unroll
        for (int i = 0; i < 4; ++i) {
            int no = 4 * r + i;
            if (no < cnt) {
                int node = nb0 + no;
                float di = dinv[node];
                s2sp4[node] = make_float4(p0[i] * di, p1[i] * di, p2[i] * di, 0.f);
            }
        }
    }
}

// --- pull conv2 + bias + filter; 2 nodes per wave, 32-lane reduce ---
__global__ __launch_bounds__(256) void k_pull2(
        const unsigned* __restrict__ st, const int* __restrict__ rs,
        const int* __restrict__ rl, const float* __restrict__ dinv,
        const float4* __restrict__ s2sp4, const float* __restrict__ b2,
        const float* __restrict__ ef, float* __restrict__ out, int n) {
    int t = threadIdx.x;
    int w = t >> 6, lane = t & 63;
    int half = lane >> 5, sl = lane & 31;
    int d = blockIdx.x * 8 + w * 2 + half;
    if (d >= n) return;
    int beg = rs[d], end = beg + rl[d];
    float a0 = 0.f, a1 = 0.f, a2 = 0.f;
    for (int j = beg + sl; j < end; j += 32) {
        float4 v = s2sp4[st[j] & SMASK];           // 1.6 MB: L2-resident gather
        a0 += v.x; a1 += v.y; a2 += v.z;
    }
    #pragma unroll
    for (int off = 16; off; off >>= 1) {
        a0 += __shfl_down(a0, off, 32);
        a1 += __shfl_down(a1, off, 32);
        a2 += __shfl_down(a2, off, 32);
    }
    if (sl == 0) {
        float dd = dinv[d];
        float4 self = s2sp4[d];
        out[d * NC + 0] = (dd * (a0 + self.x) + b2[0]) * ef[0];
        out[d * NC + 1] = (dd * (a1 + self.y) + b2[1]) * ef[1];
        out[d * NC + 2] = (dd * (a2 + self.z) + b2[2]) * ef[2];
    }
}

extern "C" void kernel_launch(void* const* d_in, const int* in_sizes, int n_in,
                              void* d_out, int out_size, void* d_ws, size_t ws_size,
                              hipStream_t stream) {
    const float* x  = (const float*)d_in[0];
    const int*   ei = (const int*)d_in[1];
    const float* W1 = (const float*)d_in[2];
    const float* b1 = (const float*)d_in[3];
    const float* Wf = (const float*)d_in[4];
    const float* bf = (const float*)d_in[5];
    const float* W2 = (const float*)d_in[6];
    const float* b2 = (const float*)d_in[7];
    const float* ef = (const float*)d_in[8];

    int n  = in_sizes[0] / NF;
    int ne = in_sizes[1] / 2;
    const int* src = ei;
    const int* dst = ei + ne;
    int nbk = (n + BK - 1) >> 8;                   // 391

    auto al = [](size_t v) { return (v + 255) & ~(size_t)255; };
    char* ws = (char*)d_ws;
    size_t off = 0;
    unsigned* staging = (unsigned*)(ws + off); off += al((size_t)nbk * CAP * 4);   // 16 MB
    float*    s2sp    = (float*)(ws + off);    off += al((size_t)n * 4 * 4);
    float*    dinv    = (float*)(ws + off);    off += al((size_t)n * 4);
    int*      rsb     = (int*)(ws + off);      off += al((size_t)n * 4);
    int*      rlb     = (int*)(ws + off);      off += al((size_t)n * 4);
    int*      gcur    = (int*)(ws + off);      off += al((size_t)MAXNBK * 4);
    float* out = (float*)d_out;

    int binblocks = (ne + EPB - 1) / EPB;          // 500

    k_zero <<<2, 256, 0, stream>>>(gcur, MAXNBK);
    k_bin2 <<<binblocks, 512, 0, stream>>>(src, dst, gcur, staging, ne, nbk);
    k_sort <<<nbk, 512, 0, stream>>>(staging, gcur, rsb, rlb, dinv, n);
    k_fused<<<(n + 127) / 128, 256, 0, stream>>>(staging, rsb, rlb, dinv,
                                                 (const float4*)x, W1, b1, Wf, bf, W2,
                                                 (float4*)s2sp, n);
    k_pull2<<<(n + 7) / 8, 256, 0, stream>>>(staging, rsb, rlb, dinv,
                                             (const float4*)s2sp, b2, ef, out, n);
}

// Round 17
// 203.423 us; speedup vs baseline: 1.1463x; 1.1463x over previous
//
#include <hip/hip_runtime.h>

#define NF 40
#define NF4 10
#define H  64
#define NC 3
#define BK 256        // nodes per bucket (dst>>8)
#define CAP 10240     // staging capacity per bucket (mean 8192, +22 sigma)
#define MAXNBK 512
#define SMASK 0xFFFFFu
#define EPB 6400      // edges per k_bin2 block

__device__ __forceinline__ void add4(float4& a, const float4& u) {
    a.x += u.x; a.y += u.y; a.z += u.z; a.w += u.w;
}

// --- zero ints ---
__global__ void k_zero(int* __restrict__ p, int n) {
    int i = blockIdx.x * blockDim.x + threadIdx.x;
    if (i < n) p[i] = 0;
}

// --- partition: block-local bucket sort in LDS, then coalesced window writes ---
__global__ __launch_bounds__(512) void k_bin2(const int* __restrict__ src,
                                              const int* __restrict__ dst,
                                              int* __restrict__ gcur,
                                              unsigned* __restrict__ staging,
                                              int ne, int nbk) {
    __shared__ unsigned sorted[EPB];               // 25.6 KB
    __shared__ unsigned short sbk[EPB];            // 12.8 KB
    __shared__ int cnt[MAXNBK];
    __shared__ int tsum[MAXNBK];
    __shared__ int lstart[MAXNBK];
    __shared__ int gbase[MAXNBK];
    __shared__ int cur[MAXNBK];
    int t = threadIdx.x;
    int e0 = blockIdx.x * EPB;
    int m = min(EPB, ne - e0);
    if (m <= 0) return;

    for (int b = t; b < MAXNBK; b += 512) cnt[b] = 0;
    __syncthreads();
    for (int j = t; j < m; j += 512)               // pass 1: bucket histogram
        atomicAdd(&cnt[dst[e0 + j] >> 8], 1);
    __syncthreads();
    int val = (t < nbk) ? cnt[t] : 0;              // block-wide exclusive scan (512)
    tsum[t] = val;
    __syncthreads();
    for (int off = 1; off < 512; off <<= 1) {
        int a = (t >= off) ? tsum[t - off] : 0;
        __syncthreads();
        tsum[t] += a;
        __syncthreads();
    }
    lstart[t] = tsum[t] - val;
    cur[t] = tsum[t] - val;
    if (t < nbk) gbase[t] = val ? atomicAdd(&gcur[t], val) : 0;   // reserve windows
    __syncthreads();
    for (int j = t; j < m; j += 512) {             // pass 2: LDS scatter (bucket order)
        int d = dst[e0 + j], s = src[e0 + j];
        int b = d >> 8;
        int p = atomicAdd(&cur[b], 1);
        sorted[p] = ((unsigned)(d & 255) << 20) | (unsigned)s;
        sbk[p] = (unsigned short)b;
    }
    __syncthreads();
    for (int j = t; j < m; j += 512) {             // pass 3: near-coalesced writes
        int b = sbk[j];
        staging[(size_t)b * CAP + gbase[b] + (j - lstart[b])] = sorted[j];
    }
}

// --- per-bucket sort by dlocal (in place via LDS bounce); emits rs/rl/dinv ---
__global__ __launch_bounds__(512) void k_sort(unsigned* __restrict__ staging,
                                              const int* __restrict__ gcur,
                                              int* __restrict__ rs, int* __restrict__ rl,
                                              float* __restrict__ dinv, int n) {
    __shared__ unsigned buf[CAP];      // 40 KB bounce buffer
    __shared__ int cnt[BK];
    __shared__ int scn[BK];
    __shared__ int cur[BK];
    int b = blockIdx.x, t = threadIdx.x;
    int ebase = b * CAP;
    int rlen = gcur[b];
    for (int j = t; j < rlen; j += 512) buf[j] = staging[ebase + j];
    if (t < BK) cnt[t] = 0;
    __syncthreads();
    for (int j = t; j < rlen; j += 512)
        atomicAdd(&cnt[buf[j] >> 20], 1);
    __syncthreads();
    if (t < BK) scn[t] = cnt[t];
    __syncthreads();
    for (int off = 1; off < BK; off <<= 1) {       // inclusive Hillis-Steele
        int a = (t < BK && t >= off) ? scn[t - off] : 0;
        __syncthreads();
        if (t < BK) scn[t] += a;
        __syncthreads();
    }
    if (t < BK) {
        int deg = cnt[t];
        int excl = scn[t] - deg;
        cur[t] = excl;
        int node = b * BK + t;
        if (node < n) {
            rs[node] = ebase + excl;
            rl[node] = deg;
            dinv[node] = rsqrtf((float)(deg + 1));
        }
    }
    __syncthreads();
    for (int j = t; j < rlen; j += 512) {          // scatter back sorted by dlocal
        unsigned e = buf[j];
        int p = atomicAdd(&cur[e >> 20], 1);
        staging[ebase + p] = e;
    }
}

// --- pull conv1: ax[d] = dd*(sum_s x[s]*dinv[s] + x[d]*dd); 6 nbr slots x 10 lanes ---
__global__ __launch_bounds__(256) void k_pull1(
        const unsigned* __restrict__ st, const int* __restrict__ rs,
        const int* __restrict__ rl, const float* __restrict__ dinv,
        const float4* __restrict__ x4, float4* __restrict__ ax4, int n) {
    __shared__ float4 red[4][64];
    int t = threadIdx.x;
    int w = t >> 6, lane = t & 63;
    int d = blockIdx.x * 4 + w;
    if (d >= n) return;
    int g = lane / 10, f = lane - g * 10;          // 6 slots x 10 float4-lanes
    int beg = rs[d], len = rl[d];
    float dd = dinv[d];
    float4 acc = make_float4(0.f, 0.f, 0.f, 0.f);
    if (g < 6) {
        int j = beg + g, end = beg + len;
        for (; j + 6 < end; j += 12) {             // 2 independent gathers in flight
            unsigned eA = st[j], eB = st[j + 6];
            int sA = (int)(eA & SMASK), sB = (int)(eB & SMASK);
            float wA = dinv[sA], wB = dinv[sB];
            float4 a4 = x4[sA * NF4 + f];
            float4 b4 = x4[sB * NF4 + f];
            acc.x += a4.x * wA + b4.x * wB;
            acc.y += a4.y * wA + b4.y * wB;
            acc.z += a4.z * wA + b4.z * wB;
            acc.w += a4.w * wA + b4.w * wB;
        }
        if (j < end) {
            unsigned e = st[j];
            int s = (int)(e & SMASK);
            float wv = dinv[s];
            float4 v = x4[s * NF4 + f];
            acc.x += v.x * wv; acc.y += v.y * wv;
            acc.z += v.z * wv; acc.w += v.w * wv;
        }
    }
    red[w][lane] = acc;
    // same-wave LDS RAW: in-order DS pipe + compiler lgkmcnt; no block barrier needed
    if (lane < NF4) {
        float4 tot = red[w][lane];
        #pragma unroll
        for (int gg = 1; gg < 6; ++gg) add4(tot, red[w][gg * 10 + lane]);
        float4 self = x4[d * NF4 + lane];
        float4 o;
        o.x = dd * (tot.x + self.x * dd);
        o.y = dd * (tot.y + self.y * dd);
        o.z = dd * (tot.z + self.z * dd);
        o.w = dd * (tot.w + self.w * dd);
        ax4[d * NF4 + lane] = o;
    }
}

// --- fused per-node MLP v4: register-tiled wave-GEMM ---
// Wf (hot 64-iter loop) staged in LDS; W1 (40-iter loop) from global (L1 broadcast).
// LDS = hT 32 KB + Wf 16 KB = 48 KB -> 3 blocks/CU (vs v2's 2).
// lane=(r,c): owns nodes 4r..4r+3, cols 8c..8c+7; acc[4][8].
__global__ __launch_bounds__(256, 3) void k_node(
        const float4* __restrict__ ax4,
        const float* __restrict__ W1, const float* __restrict__ b1,
        const float* __restrict__ Wf, const float* __restrict__ bf,
        const float* __restrict__ W2, const float* __restrict__ dinv,
        float4* __restrict__ s2sp4, int n) {
    __shared__ float lWf[H * H];                   // 16 KB, [k][col] (native layout)
    __shared__ float hT[4][H * 32];                // 8 KB/wave; low NF*32 doubles as axT
    int t = threadIdx.x, w = t >> 6, lane = t & 63;
    int r = lane & 7, c = lane >> 3;

    for (int i = t; i < H * H; i += 256) lWf[i] = Wf[i];
    __syncthreads();                               // all waves pass before any returns

    int nb0 = (blockIdx.x * 4 + w) * 32;
    if (nb0 >= n) return;
    int cnt = min(32, n - nb0);

    float bb[8], bfv[8], w2s[8][3];
    #pragma unroll
    for (int j = 0; j < 8; ++j) {
        bb[j]  = b1[8 * c + j];
        bfv[j] = bf[8 * c + j];
        w2s[j][0] = W2[(8 * c + j) * NC + 0];
        w2s[j][1] = W2[(8 * c + j) * NC + 1];
        w2s[j][2] = W2[(8 * c + j) * NC + 2];
    }

    // stage ax rows (coalesced float4) transposed into axT[k][node] (= hT[w] low)
    float* axT = &hT[w][0];
    #pragma unroll
    for (int i = 0; i < 5; ++i) {
        int idx = lane + 64 * i;                   // 0..319 = 32 nodes x 10 float4
        int no = idx / NF4, q = idx - no * NF4;
        float4 a = make_float4(0.f, 0.f, 0.f, 0.f);
        if (no < cnt) a = ax4[(size_t)(nb0 + no) * NF4 + q];
        axT[(4 * q + 0) * 32 + no] = a.x;
        axT[(4 * q + 1) * 32 + no] = a.y;
        axT[(4 * q + 2) * 32 + no] = a.z;
        axT[(4 * q + 3) * 32 + no] = a.w;
    }
    // same-wave in-order DS: k-loop reads below see the staging writes

    // ---- layer 1: h = relu(ax*W1 + b1), K=40; W1 from global (L1-hot) ----
    float acc[4][8];
    #pragma unroll
    for (int i = 0; i < 4; ++i)
        #pragma unroll
        for (int j = 0; j < 8; ++j) acc[i][j] = bb[j];
    for (int k = 0; k < NF; ++k) {
        float4 a   = *(const float4*)&axT[k * 32 + 4 * r];
        float4 blo = *(const float4*)&W1[k * H + 8 * c];
        float4 bhi = *(const float4*)&W1[k * H + 8 * c + 4];
        float av[4] = {a.x, a.y, a.z, a.w};
        float bv[8] = {blo.x, blo.y, blo.z, blo.w, bhi.x, bhi.y, bhi.z, bhi.w};
        #pragma unroll
        for (int i = 0; i < 4; ++i)
            #pragma unroll
            for (int j = 0; j < 8; ++j) acc[i][j] = fmaf(av[i], bv[j], acc[i][j]);
    }
    // write h transposed (hT[col][node]); all L1 reads completed (program order)
    #pragma unroll
    for (int j = 0; j < 8; ++j) {
        float4 hv = make_float4(fmaxf(acc[0][j], 0.f), fmaxf(acc[1][j], 0.f),
                                fmaxf(acc[2][j], 0.f), fmaxf(acc[3][j], 0.f));
        *(float4*)&hT[w][(8 * c + j) * 32 + 4 * r] = hv;
    }

    // ---- layer 2: mem = h*Wf + bf, K=64; Wf from LDS ----
    float acc2[4][8];
    #pragma unroll
    for (int i = 0; i < 4; ++i)
        #pragma unroll
        for (int j = 0; j < 8; ++j) acc2[i][j] = bfv[j];
    for (int k = 0; k < H; ++k) {
        float4 a   = *(const float4*)&hT[w][k * 32 + 4 * r];
        float4 blo = *(const float4*)&lWf[k * H + 8 * c];
        float4 bhi = *(const float4*)&lWf[k * H + 8 * c + 4];
        float av[4] = {a.x, a.y, a.z, a.w};
        float bv[8] = {blo.x, blo.y, blo.z, blo.w, bhi.x, bhi.y, bhi.z, bhi.w};
        #pragma unroll
        for (int i = 0; i < 4; ++i)
            #pragma unroll
            for (int j = 0; j < 8; ++j) acc2[i][j] = fmaf(av[i], bv[j], acc2[i][j]);
    }

    // ---- spike + W2: per-lane partials over its 8 cols, xor-reduce over c ----
    float p0[4], p1[4], p2[4];
    #pragma unroll
    for (int i = 0; i < 4; ++i) { p0[i] = 0.f; p1[i] = 0.f; p2[i] = 0.f; }
    #pragma unroll
    for (int i = 0; i < 4; ++i)
        #pragma unroll
        for (int j = 0; j < 8; ++j) {
            float s = (acc2[i][j] >= 0.5f) ? 1.f : 0.f;
            p0[i] = fmaf(s, w2s[j][0], p0[i]);
            p1[i] = fmaf(s, w2s[j][1], p1[i]);
            p2[i] = fmaf(s, w2s[j][2], p2[i]);
        }
    #pragma unroll
    for (int off = 8; off < 64; off <<= 1) {
        #pragma unroll
        for (int i = 0; i < 4; ++i) {
            p0[i] += __shfl_xor(p0[i], off);
            p1[i] += __shfl_xor(p1[i], off);
            p2[i] += __shfl_xor(p2[i], off);
        }
    }
    if (c == 0) {
        #pragma unroll
        for (int i = 0; i < 4; ++i) {
            int no = 4 * r + i;
            if (no < cnt) {
                int node = nb0 + no;
                float di = dinv[node];
                s2sp4[node] = make_float4(p0[i] * di, p1[i] * di, p2[i] * di, 0.f);
            }
        }
    }
}

// --- pull conv2 + bias + filter; 2 nodes per wave, 32-lane reduce ---
__global__ __launch_bounds__(256) void k_pull2(
        const unsigned* __restrict__ st, const int* __restrict__ rs,
        const int* __restrict__ rl, const float* __restrict__ dinv,
        const float4* __restrict__ s2sp4, const float* __restrict__ b2,
        const float* __restrict__ ef, float* __restrict__ out, int n) {
    int t = threadIdx.x;
    int w = t >> 6, lane = t & 63;
    int half = lane >> 5, sl = lane & 31;
    int d = blockIdx.x * 8 + w * 2 + half;
    if (d >= n) return;
    int beg = rs[d], end = beg + rl[d];
    float a0 = 0.f, a1 = 0.f, a2 = 0.f;
    for (int j = beg + sl; j < end; j += 32) {
        float4 v = s2sp4[st[j] & SMASK];           // 1.6 MB: L2-resident gather
        a0 += v.x; a1 += v.y; a2 += v.z;
    }
    #pragma unroll
    for (int off = 16; off; off >>= 1) {
        a0 += __shfl_down(a0, off, 32);
        a1 += __shfl_down(a1, off, 32);
        a2 += __shfl_down(a2, off, 32);
    }
    if (sl == 0) {
        float dd = dinv[d];
        float4 self = s2sp4[d];
        out[d * NC + 0] = (dd * (a0 + self.x) + b2[0]) * ef[0];
        out[d * NC + 1] = (dd * (a1 + self.y) + b2[1]) * ef[1];
        out[d * NC + 2] = (dd * (a2 + self.z) + b2[2]) * ef[2];
    }
}

extern "C" void kernel_launch(void* const* d_in, const int* in_sizes, int n_in,
                              void* d_out, int out_size, void* d_ws, size_t ws_size,
                              hipStream_t stream) {
    const float* x  = (const float*)d_in[0];
    const int*   ei = (const int*)d_in[1];
    const float* W1 = (const float*)d_in[2];
    const float* b1 = (const float*)d_in[3];
    const float* Wf = (const float*)d_in[4];
    const float* bf = (const float*)d_in[5];
    const float* W2 = (const float*)d_in[6];
    const float* b2 = (const float*)d_in[7];
    const float* ef = (const float*)d_in[8];

    int n  = in_sizes[0] / NF;
    int ne = in_sizes[1] / 2;
    const int* src = ei;
    const int* dst = ei + ne;
    int nbk = (n + BK - 1) >> 8;                   // 391

    auto al = [](size_t v) { return (v + 255) & ~(size_t)255; };
    char* ws = (char*)d_ws;
    size_t off = 0;
    unsigned* staging = (unsigned*)(ws + off); off += al((size_t)nbk * CAP * 4);   // 16 MB
    float*    axbuf   = (float*)(ws + off);    off += al((size_t)n * NF * 4);      // 16 MB
    float*    s2sp    = (float*)(ws + off);    off += al((size_t)n * 4 * 4);
    float*    dinv    = (float*)(ws + off);    off += al((size_t)n * 4);
    int*      rsb     = (int*)(ws + off);      off += al((size_t)n * 4);
    int*      rlb     = (int*)(ws + off);      off += al((size_t)n * 4);
    int*      gcur    = (int*)(ws + off);      off += al((size_t)MAXNBK * 4);
    float* out = (float*)d_out;

    int binblocks = (ne + EPB - 1) / EPB;          // 500

    k_zero <<<2, 256, 0, stream>>>(gcur, MAXNBK);
    k_bin2 <<<binblocks, 512, 0, stream>>>(src, dst, gcur, staging, ne, nbk);
    k_sort <<<nbk, 512, 0, stream>>>(staging, gcur, rsb, rlb, dinv, n);
    k_pull1<<<(n + 3) / 4, 256, 0, stream>>>(staging, rsb, rlb, dinv,
                                             (const float4*)x, (float4*)axbuf, n);
    k_node <<<(n + 127) / 128, 256, 0, stream>>>(
        (const float4*)axbuf, W1, b1, Wf, bf, W2, dinv, (float4*)s2sp, n);
    k_pull2<<<(n + 7) / 8, 256, 0, stream>>>(staging, rsb, rlb, dinv,
                                             (const float4*)s2sp, b2, ef, out, n);
}

// Round 18
// 197.997 us; speedup vs baseline: 1.1777x; 1.0274x over previous
//
#include <hip/hip_runtime.h>

#define NF 40
#define NF4 10
#define H  64
#define NC 3
#define BK 256        // nodes per bucket (dst>>8)
#define CAP 10240     // staging capacity per bucket (mean 8192, +22 sigma)
#define MAXNBK 512
#define SMASK 0xFFFFFu
#define EPB 6400      // edges per k_bin2 block (13*512 = 6656 >= EPB covers all)

__device__ __forceinline__ void add4(float4& a, const float4& u) {
    a.x += u.x; a.y += u.y; a.z += u.z; a.w += u.w;
}

// --- zero ints ---
__global__ void k_zero(int* __restrict__ p, int n) {
    int i = blockIdx.x * blockDim.x + threadIdx.x;
    if (i < n) p[i] = 0;
}

// --- partition: edges register-cached, block-local bucket sort in LDS,
//     then near-coalesced window writes ---
__global__ __launch_bounds__(512) void k_bin2(const int* __restrict__ src,
                                              const int* __restrict__ dst,
                                              int* __restrict__ gcur,
                                              unsigned* __restrict__ staging,
                                              int ne, int nbk) {
    __shared__ unsigned sorted[EPB];               // 25.6 KB
    __shared__ unsigned short sbk[EPB];            // 12.8 KB
    __shared__ int cnt[MAXNBK];
    __shared__ int tsum[MAXNBK];
    __shared__ int lstart[MAXNBK];
    __shared__ int gbase[MAXNBK];
    __shared__ int cur[MAXNBK];
    int t = threadIdx.x;
    int e0 = blockIdx.x * EPB;
    int m = min(EPB, ne - e0);
    if (m <= 0) return;

    for (int b = t; b < MAXNBK; b += 512) cnt[b] = 0;
    __syncthreads();
    int d13[13], s13[13];                          // register cache: read src/dst ONCE
    #pragma unroll
    for (int u = 0; u < 13; ++u) {
        int j = t + u * 512;
        bool v = (j < m);
        d13[u] = v ? dst[e0 + j] : -1;
        s13[u] = v ? src[e0 + j] : 0;
        if (v) atomicAdd(&cnt[d13[u] >> 8], 1);
    }
    __syncthreads();
    int val = (t < nbk) ? cnt[t] : 0;              // block-wide exclusive scan (512)
    tsum[t] = val;
    __syncthreads();
    for (int off = 1; off < 512; off <<= 1) {
        int a = (t >= off) ? tsum[t - off] : 0;
        __syncthreads();
        tsum[t] += a;
        __syncthreads();
    }
    lstart[t] = tsum[t] - val;
    cur[t] = tsum[t] - val;
    if (t < nbk) gbase[t] = val ? atomicAdd(&gcur[t], val) : 0;   // reserve windows
    __syncthreads();
    #pragma unroll
    for (int u = 0; u < 13; ++u) {                 // LDS scatter (bucket order)
        if (d13[u] >= 0) {
            int b = d13[u] >> 8;
            int p = atomicAdd(&cur[b], 1);
            sorted[p] = ((unsigned)(d13[u] & 255) << 20) | (unsigned)s13[u];
            sbk[p] = (unsigned short)b;
        }
    }
    __syncthreads();
    for (int j = t; j < m; j += 512) {             // near-coalesced window writes
        int b = sbk[j];
        staging[(size_t)b * CAP + gbase[b] + (j - lstart[b])] = sorted[j];
    }
}

// --- per-bucket sort by dlocal (in place via LDS bounce); emits rs/rl/dinv ---
__global__ __launch_bounds__(512) void k_sort(unsigned* __restrict__ staging,
                                              const int* __restrict__ gcur,
                                              int* __restrict__ rs, int* __restrict__ rl,
                                              float* __restrict__ dinv, int n) {
    __shared__ __align__(16) unsigned buf[CAP];    // 40 KB bounce buffer
    __shared__ int cnt[BK];
    __shared__ int scn[BK];
    __shared__ int cur[BK];
    int b = blockIdx.x, t = threadIdx.x;
    int ebase = b * CAP;                           // CAP%4==0 -> 16B-aligned rows
    int rlen = gcur[b];
    const uint4* stg4 = (const uint4*)(staging + ebase);
    int m4 = rlen >> 2;
    for (int j = t; j < m4; j += 512)              // vectorized 16B loads
        *(uint4*)&buf[j * 4] = stg4[j];
    for (int j = (m4 << 2) + t; j < rlen; j += 512)
        buf[j] = staging[ebase + j];
    if (t < BK) cnt[t] = 0;
    __syncthreads();
    for (int j = t; j < rlen; j += 512)
        atomicAdd(&cnt[buf[j] >> 20], 1);
    __syncthreads();
    if (t < BK) scn[t] = cnt[t];
    __syncthreads();
    for (int off = 1; off < BK; off <<= 1) {       // inclusive Hillis-Steele
        int a = (t < BK && t >= off) ? scn[t - off] : 0;
        __syncthreads();
        if (t < BK) scn[t] += a;
        __syncthreads();
    }
    if (t < BK) {
        int deg = cnt[t];
        int excl = scn[t] - deg;
        cur[t] = excl;
        int node = b * BK + t;
        if (node < n) {
            rs[node] = ebase + excl;
            rl[node] = deg;
            dinv[node] = rsqrtf((float)(deg + 1));
        }
    }
    __syncthreads();
    for (int j = t; j < rlen; j += 512) {          // scatter back sorted by dlocal
        unsigned e = buf[j];
        int p = atomicAdd(&cur[e >> 20], 1);
        staging[ebase + p] = e;
    }
}

// --- pull conv1: ax[d] = dd*(sum_s x[s]*dinv[s] + x[d]*dd); 6 nbr slots x 10 lanes ---
__global__ __launch_bounds__(256) void k_pull1(
        const unsigned* __restrict__ st, const int* __restrict__ rs,
        const int* __restrict__ rl, const float* __restrict__ dinv,
        const float4* __restrict__ x4, float4* __restrict__ ax4, int n) {
    __shared__ float4 red[4][64];
    int t = threadIdx.x;
    int w = t >> 6, lane = t & 63;
    int d = blockIdx.x * 4 + w;
    if (d >= n) return;
    int g = lane / 10, f = lane - g * 10;          // 6 slots x 10 float4-lanes
    int beg = rs[d], len = rl[d];
    float dd = dinv[d];
    float4 acc = make_float4(0.f, 0.f, 0.f, 0.f);
    if (g < 6) {
        int j = beg + g, end = beg + len;
        for (; j + 6 < end; j += 12) {             // 2 independent gathers in flight
            unsigned eA = st[j], eB = st[j + 6];
            int sA = (int)(eA & SMASK), sB = (int)(eB & SMASK);
            float wA = dinv[sA], wB = dinv[sB];
            float4 a4 = x4[sA * NF4 + f];
            float4 b4 = x4[sB * NF4 + f];
            acc.x += a4.x * wA + b4.x * wB;
            acc.y += a4.y * wA + b4.y * wB;
            acc.z += a4.z * wA + b4.z * wB;
            acc.w += a4.w * wA + b4.w * wB;
        }
        if (j < end) {
            unsigned e = st[j];
            int s = (int)(e & SMASK);
            float wv = dinv[s];
            float4 v = x4[s * NF4 + f];
            acc.x += v.x * wv; acc.y += v.y * wv;
            acc.z += v.z * wv; acc.w += v.w * wv;
        }
    }
    red[w][lane] = acc;
    // same-wave LDS RAW: in-order DS pipe + compiler lgkmcnt; no block barrier needed
    if (lane < NF4) {
        float4 tot = red[w][lane];
        #pragma unroll
        for (int gg = 1; gg < 6; ++gg) add4(tot, red[w][gg * 10 + lane]);
        float4 self = x4[d * NF4 + lane];
        float4 o;
        o.x = dd * (tot.x + self.x * dd);
        o.y = dd * (tot.y + self.y * dd);
        o.z = dd * (tot.z + self.z * dd);
        o.w = dd * (tot.w + self.w * dd);
        ax4[d * NF4 + lane] = o;
    }
}

// --- fused per-node MLP v4: register-tiled wave-GEMM ---
// Wf (hot 64-iter loop) staged in LDS; W1 (40-iter loop) from global (L1 broadcast).
// LDS = hT 32 KB + Wf 16 KB = 48 KB -> 3 blocks/CU.
// lane=(r,c): owns nodes 4r..4r+3, cols 8c..8c+7; acc[4][8].
__global__ __launch_bounds__(256, 3) void k_node(
        const float4* __restrict__ ax4,
        const float* __restrict__ W1, const float* __restrict__ b1,
        const float* __restrict__ Wf, const float* __restrict__ bf,
        const float* __restrict__ W2, const float* __restrict__ dinv,
        float4* __restrict__ s2sp4, int n) {
    __shared__ float lWf[H * H];                   // 16 KB, [k][col] (native layout)
    __shared__ float hT[4][H * 32];                // 8 KB/wave; low NF*32 doubles as axT
    int t = threadIdx.x, w = t >> 6, lane = t & 63;
    int r = lane & 7, c = lane >> 3;

    for (int i = t; i < H * H; i += 256) lWf[i] = Wf[i];
    __syncthreads();                               // all waves pass before any returns

    int nb0 = (blockIdx.x * 4 + w) * 32;
    if (nb0 >= n) return;
    int cnt = min(32, n - nb0);

    float bb[8], bfv[8], w2s[8][3];
    #pragma unroll
    for (int j = 0; j < 8; ++j) {
        bb[j]  = b1[8 * c + j];
        bfv[j] = bf[8 * c + j];
        w2s[j][0] = W2[(8 * c + j) * NC + 0];
        w2s[j][1] = W2[(8 * c + j) * NC + 1];
        w2s[j][2] = W2[(8 * c + j) * NC + 2];
    }

    // stage ax rows (coalesced float4) transposed into axT[k][node] (= hT[w] low)
    float* axT = &hT[w][0];
    #pragma unroll
    for (int i = 0; i < 5; ++i) {
        int idx = lane + 64 * i;                   // 0..319 = 32 nodes x 10 float4
        int no = idx / NF4, q = idx - no * NF4;
        float4 a = make_float4(0.f, 0.f, 0.f, 0.f);
        if (no < cnt) a = ax4[(size_t)(nb0 + no) * NF4 + q];
        axT[(4 * q + 0) * 32 + no] = a.x;
        axT[(4 * q + 1) * 32 + no] = a.y;
        axT[(4 * q + 2) * 32 + no] = a.z;
        axT[(4 * q + 3) * 32 + no] = a.w;
    }
    // same-wave in-order DS: k-loop reads below see the staging writes

    // ---- layer 1: h = relu(ax*W1 + b1), K=40; W1 from global (L1-hot) ----
    float acc[4][8];
    #pragma unroll
    for (int i = 0; i < 4; ++i)
        #pragma unroll
        for (int j = 0; j < 8; ++j) acc[i][j] = bb[j];
    for (int k = 0; k < NF; ++k) {
        float4 a   = *(const float4*)&axT[k * 32 + 4 * r];
        float4 blo = *(const float4*)&W1[k * H + 8 * c];
        float4 bhi = *(const float4*)&W1[k * H + 8 * c + 4];
        float av[4] = {a.x, a.y, a.z, a.w};
        float bv[8] = {blo.x, blo.y, blo.z, blo.w, bhi.x, bhi.y, bhi.z, bhi.w};
        #pragma unroll
        for (int i = 0; i < 4; ++i)
            #pragma unroll
            for (int j = 0; j < 8; ++j) acc[i][j] = fmaf(av[i], bv[j], acc[i][j]);
    }
    // write h transposed (hT[col][node]); all L1 reads completed (program order)
    #pragma unroll
    for (int j = 0; j < 8; ++j) {
        float4 hv = make_float4(fmaxf(acc[0][j], 0.f), fmaxf(acc[1][j], 0.f),
                                fmaxf(acc[2][j], 0.f), fmaxf(acc[3][j], 0.f));
        *(float4*)&hT[w][(8 * c + j) * 32 + 4 * r] = hv;
    }

    // ---- layer 2: mem = h*Wf + bf, K=64; Wf from LDS ----
    float acc2[4][8];
    #pragma unroll
    for (int i = 0; i < 4; ++i)
        #pragma unroll
        for (int j = 0; j < 8; ++j) acc2[i][j] = bfv[j];
    for (int k = 0; k < H; ++k) {
        float4 a   = *(const float4*)&hT[w][k * 32 + 4 * r];
        float4 blo = *(const float4*)&lWf[k * H + 8 * c];
        float4 bhi = *(const float4*)&lWf[k * H + 8 * c + 4];
        float av[4] = {a.x, a.y, a.z, a.w};
        float bv[8] = {blo.x, blo.y, blo.z, blo.w, bhi.x, bhi.y, bhi.z, bhi.w};
        #pragma unroll
        for (int i = 0; i < 4; ++i)
            #pragma unroll
            for (int j = 0; j < 8; ++j) acc2[i][j] = fmaf(av[i], bv[j], acc2[i][j]);
    }

    // ---- spike + W2: per-lane partials over its 8 cols, xor-reduce over c ----
    float p0[4], p1[4], p2[4];
    #pragma unroll
    for (int i = 0; i < 4; ++i) { p0[i] = 0.f; p1[i] = 0.f; p2[i] = 0.f; }
    #pragma unroll
    for (int i = 0; i < 4; ++i)
        #pragma unroll
        for (int j = 0; j < 8; ++j) {
            float s = (acc2[i][j] >= 0.5f) ? 1.f : 0.f;
            p0[i] = fmaf(s, w2s[j][0], p0[i]);
            p1[i] = fmaf(s, w2s[j][1], p1[i]);
            p2[i] = fmaf(s, w2s[j][2], p2[i]);
        }
    #pragma unroll
    for (int off = 8; off < 64; off <<= 1) {
        #pragma unroll
        for (int i = 0; i < 4; ++i) {
            p0[i] += __shfl_xor(p0[i], off);
            p1[i] += __shfl_xor(p1[i], off);
            p2[i] += __shfl_xor(p2[i], off);
        }
    }
    if (c == 0) {
        #pragma unroll
        for (int i = 0; i < 4; ++i) {
            int no = 4 * r + i;
            if (no < cnt) {
                int node = nb0 + no;
                float di = dinv[node];
                s2sp4[node] = make_float4(p0[i] * di, p1[i] * di, p2[i] * di, 0.f);
            }
        }
    }
}

// --- pull conv2 + bias + filter; 4 nodes per wave, 16-lane reduce ---
__global__ __launch_bounds__(256) void k_pull2(
        const unsigned* __restrict__ st, const int* __restrict__ rs,
        const int* __restrict__ rl, const float* __restrict__ dinv,
        const float4* __restrict__ s2sp4, const float* __restrict__ b2,
        const float* __restrict__ ef, float* __restrict__ out, int n) {
    int t = threadIdx.x;
    int w = t >> 6, lane = t & 63;
    int q = lane >> 4, sl = lane & 15;
    int d = blockIdx.x * 16 + w * 4 + q;
    if (d >= n) return;
    int beg = rs[d], end = beg + rl[d];
    float a0 = 0.f, a1 = 0.f, a2 = 0.f;
    for (int j = beg + sl; j < end; j += 16) {
        float4 v = s2sp4[st[j] & SMASK];           // 1.6 MB: L2-resident gather
        a0 += v.x; a1 += v.y; a2 += v.z;
    }
    #pragma unroll
    for (int off = 8; off; off >>= 1) {
        a0 += __shfl_down(a0, off, 16);
        a1 += __shfl_down(a1, off, 16);
        a2 += __shfl_down(a2, off, 16);
    }
    if (sl == 0) {
        float dd = dinv[d];
        float4 self = s2sp4[d];
        out[d * NC + 0] = (dd * (a0 + self.x) + b2[0]) * ef[0];
        out[d * NC + 1] = (dd * (a1 + self.y) + b2[1]) * ef[1];
        out[d * NC + 2] = (dd * (a2 + self.z) + b2[2]) * ef[2];
    }
}

extern "C" void kernel_launch(void* const* d_in, const int* in_sizes, int n_in,
                              void* d_out, int out_size, void* d_ws, size_t ws_size,
                              hipStream_t stream) {
    const float* x  = (const float*)d_in[0];
    const int*   ei = (const int*)d_in[1];
    const float* W1 = (const float*)d_in[2];
    const float* b1 = (const float*)d_in[3];
    const float* Wf = (const float*)d_in[4];
    const float* bf = (const float*)d_in[5];
    const float* W2 = (const float*)d_in[6];
    const float* b2 = (const float*)d_in[7];
    const float* ef = (const float*)d_in[8];

    int n  = in_sizes[0] / NF;
    int ne = in_sizes[1] / 2;
    const int* src = ei;
    const int* dst = ei + ne;
    int nbk = (n + BK - 1) >> 8;                   // 391

    auto al = [](size_t v) { return (v + 255) & ~(size_t)255; };
    char* ws = (char*)d_ws;
    size_t off = 0;
    unsigned* staging = (unsigned*)(ws + off); off += al((size_t)nbk * CAP * 4);   // 16 MB
    float*    axbuf   = (float*)(ws + off);    off += al((size_t)n * NF * 4);      // 16 MB
    float*    s2sp    = (float*)(ws + off);    off += al((size_t)n * 4 * 4);
    float*    dinv    = (float*)(ws + off);    off += al((size_t)n * 4);
    int*      rsb     = (int*)(ws + off);      off += al((size_t)n * 4);
    int*      rlb     = (int*)(ws + off);      off += al((size_t)n * 4);
    int*      gcur    = (int*)(ws + off);      off += al((size_t)MAXNBK * 4);
    float* out = (float*)d_out;

    int binblocks = (ne + EPB - 1) / EPB;          // 500

    k_zero <<<2, 256, 0, stream>>>(gcur, MAXNBK);
    k_bin2 <<<binblocks, 512, 0, stream>>>(src, dst, gcur, staging, ne, nbk);
    k_sort <<<nbk, 512, 0, stream>>>(staging, gcur, rsb, rlb, dinv, n);
    k_pull1<<<(n + 3) / 4, 256, 0, stream>>>(staging, rsb, rlb, dinv,
                                             (const float4*)x, (float4*)axbuf, n);
    k_node <<<(n + 127) / 128, 256, 0, stream>>>(
        (const float4*)axbuf, W1, b1, Wf, bf, W2, dinv, (float4*)s2sp, n);
    k_pull2<<<(n + 15) / 16, 256, 0, stream>>>(staging, rsb, rlb, dinv,
                                               (const float4*)s2sp, b2, ef, out, n);
}